// Round 3
// baseline (203.208 us; speedup 1.0000x reference)
//
#include <hip/hip_runtime.h>

typedef __bf16 bf16x4 __attribute__((ext_vector_type(4)));
typedef __bf16 bf16x8 __attribute__((ext_vector_type(8)));
typedef float f32x16 __attribute__((ext_vector_type(16)));

// ---- workspace layout (bf16 element offsets), FRAGMENT-ORDERED weights ----
// A wave's weight frag for (n-tile, k-block) is 64 lanes x 16 B = 1 KB contig:
//   elem (lane, j) at ((nt*NKBLK + kk)*64 + lane)*8 + j
//   encodes n = nt*32 + (lane&31), k = kk*16 + (lane>>5)*8 + j
#define W0F_OFF 0                 // 16 recs x 512  = 8192
#define W1F_OFF 8192              // 512 recs x 512 = 262144
#define W2F_OFF (8192 + 262144)   // 160 recs x 512 = 81920 (n>=136 zero)

// One wave per 1KB record: coalesced row reads, coalesced dwordx4 stores.
__global__ void prep_weights(const float* __restrict__ W0,
                             const float* __restrict__ W1,
                             const float* __restrict__ W2,
                             __bf16* __restrict__ ws) {
    const int wave = blockIdx.x * 8 + (threadIdx.x >> 6);   // 0..687
    const int l   = threadIdx.x & 63;
    const int col = l & 31, kh = l >> 5;
    const float* src; int nt, kk, S, nlim;
    if (wave < 16)       { src = W0; nt = wave; kk = 0;          S = 512; nlim = 512; }
    else if (wave < 528) { int r = wave - 16;  src = W1; nt = r >> 5; kk = r & 31; S = 512; nlim = 512; }
    else                 { int r = wave - 528; src = W2; nt = r >> 5; kk = r & 31; S = 136; nlim = 136; }
    const int n  = nt * 32 + col;
    const int k0 = kk * 16 + kh * 8;
    bf16x8 v;
#pragma unroll
    for (int j = 0; j < 8; ++j)
        v[j] = (n < nlim) ? (__bf16)src[(k0 + j) * S + n] : (__bf16)0.0f;
    *(bf16x8*)(ws + wave * 512 + l * 8) = v;
}

__device__ __forceinline__ float fast_tanh(float x) {
#if __has_builtin(__builtin_amdgcn_exp2f)
    float e = __builtin_amdgcn_exp2f(x * 2.885390081777926f);
#else
    float e = exp2f(x * 2.885390081777926f);
#endif
    return 1.0f - 2.0f * __builtin_amdgcn_rcpf(e + 1.0f);
}

// h LDS: [128][520] bf16 (rows 1040 B, stride 260 dwords = 4 mod 32 banks ->
// ds_read_b128 conflict-free). net LDS: [128][140] f32 overlay.
#define HSTR 520
#define NSTR 140

// R20: ANTI-PHASED DUAL-GROUP PIPELINE. Post-mortem R17-R19: MfmaUtil(30) +
// VALUBusy(32) + LDS(~15) + waits ~= 100% invariant across occupancy (4 vs 2
// waves/SIMD), arithmetic intensity (2x), and register pipelining (null) ->
// pipes never overlap because every barrier phase puts ALL waves on the same
// pipe (MFMA phases vs VALU tanh/P3 phases), and co-resident blocks run in
// lockstep (launched together). Fix: split the 128-row block into two 64-row
// groups; schedule segments pairing {MFMA phase of g_i} with {VALU phase of
// g_j}; wave-halves run the two sub-phases in OPPOSITE order (w<4 MFMA-first,
// w>=4 VALU-first). Wave w sits on SIMD w%4 -> each SIMD always has one
// MFMA-mode and one VALU-mode wave (m114 mechanism: separate waves, separate
// pipes, time = max not sum). Also: P2 is nt-major (wave=nt, both bt): W2
// L2 traffic 640KB -> 160KB per block. Peak regs = acc_a+acc_b = 128 AGPR
// (S2) + ~80 arch < 256 -> 2 waves/SIMD holds.
__global__ __launch_bounds__(512, 2)
void fused_mlp_quad(const float* __restrict__ points,
                    const float* __restrict__ b0,
                    const float* __restrict__ b1,
                    const float* __restrict__ b2,
                    const __bf16* __restrict__ ws,
                    float* __restrict__ out) {
    __shared__ __align__(16) unsigned char lds_raw[133120];
    __bf16* h  = (__bf16*)lds_raw;   // [128][HSTR] bf16 (h0, then h1 in place)
    float* net = (float*)lds_raw;    // [128][NSTR] f32 overlay (per 64-row group,
                                     // written only after that group's h consumed)

    const __bf16* w0f = ws + W0F_OFF;
    const __bf16* w1f = ws + W1F_OFF;
    const __bf16* w2f = ws + W2F_OFF;

    const int tid = threadIdx.x;
    const int w   = tid >> 6;     // wave 0..7
    const int l   = tid & 63;
    const int ln  = l & 31;
    const int hi  = l >> 5;
    const int row0 = blockIdx.x * 128;

    const int lofs = l * 8;
    const int ofs16 = (blockIdx.x >> 3) & 15;   // K-rotation (L2 de-phase)

    const f32x16 fzero = {};

    // ---- phase bodies, parameterized by group row base gb in {0, 64} ----

    auto PH0 = [&](int gb) {   // h0 = tanh(x @ W0 + b0); small MFMA + VALU
        bf16x8 bx[2];
#pragma unroll
        for (int bt = 0; bt < 2; ++bt) {
            const float* src = points + (row0 + gb + bt * 32 + ln) * 16 + hi * 8;
            float4 p0 = ((const float4*)src)[0];
            float4 p1 = ((const float4*)src)[1];
            bf16x8 v;
            v[0] = (__bf16)p0.x; v[1] = (__bf16)p0.y; v[2] = (__bf16)p0.z; v[3] = (__bf16)p0.w;
            v[4] = (__bf16)p1.x; v[5] = (__bf16)p1.y; v[6] = (__bf16)p1.z; v[7] = (__bf16)p1.w;
            bx[bt] = v;
        }
#pragma unroll
        for (int t = 0; t < 2; ++t) {
            const int ntg = w * 2 + t;
            bf16x8 wf = *(const bf16x8*)(w0f + ntg * 512 + lofs);
#pragma unroll
            for (int bt = 0; bt < 2; ++bt) {
                f32x16 acc = {};
                acc = __builtin_amdgcn_mfma_f32_32x32x16_bf16(wf, bx[bt], acc, 0, 0, 0);
#pragma unroll
                for (int rg = 0; rg < 4; ++rg) {
                    const int n0 = ntg * 32 + 8 * rg + 4 * hi;
                    float4 bias = *(const float4*)(b0 + n0);
                    bf16x4 v;
                    v[0] = (__bf16)fast_tanh(acc[4 * rg + 0] + bias.x);
                    v[1] = (__bf16)fast_tanh(acc[4 * rg + 1] + bias.y);
                    v[2] = (__bf16)fast_tanh(acc[4 * rg + 2] + bias.z);
                    v[3] = (__bf16)fast_tanh(acc[4 * rg + 3] + bias.w);
                    *(bf16x4*)(h + (gb + bt * 32 + ln) * HSTR + n0) = v;
                }
            }
        }
    };

    auto P1M = [&](int gb, f32x16 (&acc1)[2][2]) {   // acc1[bt][t] = h0 @ W1
#pragma unroll
        for (int bt = 0; bt < 2; ++bt)
#pragma unroll
            for (int t = 0; t < 2; ++t) acc1[bt][t] = fzero;
        const __bf16* arow0 = h + (gb + ln) * HSTR + hi * 8;
        const __bf16* arow1 = h + (gb + 32 + ln) * HSTR + hi * 8;
        const __bf16* wb0 = w1f + (w * 2 + 0) * 16384 + lofs;
        const __bf16* wb1 = w1f + (w * 2 + 1) * 16384 + lofs;
        for (int ks2 = 0; ks2 < 16; ++ks2) {
            const int ks = (ks2 + ofs16) & 15;
            bf16x8 aa[2][2], bb[2][2];
#pragma unroll
            for (int u = 0; u < 2; ++u) {
                const int kk = ks * 2 + u;
                aa[u][0] = *(const bf16x8*)(arow0 + kk * 16);
                aa[u][1] = *(const bf16x8*)(arow1 + kk * 16);
                bb[u][0] = *(const bf16x8*)(wb0 + kk * 512);
                bb[u][1] = *(const bf16x8*)(wb1 + kk * 512);
            }
#pragma unroll
            for (int u = 0; u < 2; ++u) {
#pragma unroll
                for (int t = 0; t < 2; ++t) {
                    acc1[0][t] = __builtin_amdgcn_mfma_f32_32x32x16_bf16(bb[u][t], aa[u][0], acc1[0][t], 0, 0, 0);
                    acc1[1][t] = __builtin_amdgcn_mfma_f32_32x32x16_bf16(bb[u][t], aa[u][1], acc1[1][t], 0, 0, 0);
                }
            }
        }
    };

    auto P1E = [&](int gb, f32x16 (&acc1)[2][2]) {   // h1 = tanh(acc1 + b1)
#pragma unroll
        for (int t = 0; t < 2; ++t)
#pragma unroll
            for (int bt = 0; bt < 2; ++bt)
#pragma unroll
                for (int rg = 0; rg < 4; ++rg) {
                    const int n0 = (w * 2 + t) * 32 + 8 * rg + 4 * hi;
                    float4 bias = *(const float4*)(b1 + n0);
                    bf16x4 v;
                    v[0] = (__bf16)fast_tanh(acc1[bt][t][4 * rg + 0] + bias.x);
                    v[1] = (__bf16)fast_tanh(acc1[bt][t][4 * rg + 1] + bias.y);
                    v[2] = (__bf16)fast_tanh(acc1[bt][t][4 * rg + 2] + bias.z);
                    v[3] = (__bf16)fast_tanh(acc1[bt][t][4 * rg + 3] + bias.w);
                    *(bf16x4*)(h + (gb + bt * 32 + ln) * HSTR + n0) = v;
                }
    };

    auto P2M = [&](int gb, f32x16 (&acc2)[2]) {   // net-acc: nt-major, wave=nt<5
        acc2[0] = fzero; acc2[1] = fzero;
        if (w < 5) {
            const __bf16* arow0 = h + (gb + ln) * HSTR + hi * 8;
            const __bf16* arow1 = h + (gb + 32 + ln) * HSTR + hi * 8;
            const __bf16* wq = w2f + w * 16384 + lofs;
            for (int ks2 = 0; ks2 < 16; ++ks2) {
                const int ks = (ks2 + ofs16) & 15;
                bf16x8 wv[2], a0[2], a1[2];
#pragma unroll
                for (int u = 0; u < 2; ++u) {
                    const int kk = ks * 2 + u;
                    wv[u] = *(const bf16x8*)(wq + kk * 512);      // 1 KB, reused x2
                    a0[u] = *(const bf16x8*)(arow0 + kk * 16);
                    a1[u] = *(const bf16x8*)(arow1 + kk * 16);
                }
#pragma unroll
                for (int u = 0; u < 2; ++u) {
                    acc2[0] = __builtin_amdgcn_mfma_f32_32x32x16_bf16(wv[u], a0[u], acc2[0], 0, 0, 0);
                    acc2[1] = __builtin_amdgcn_mfma_f32_32x32x16_bf16(wv[u], a1[u], acc2[1], 0, 0, 0);
                }
            }
        }
    };

    auto P2E = [&](int gb, f32x16 (&acc2)[2]) {   // net = acc2 + b2 (f32 LDS)
        if (w < 5) {
#pragma unroll
            for (int bt = 0; bt < 2; ++bt)
#pragma unroll
                for (int rg = 0; rg < 4; ++rg) {
                    const int n0 = w * 32 + 8 * rg + 4 * hi;
                    if (n0 < 136) {   // skip padded n (w==4, rg>0)
                        float4 bias = *(const float4*)(b2 + n0);
                        float4 v;
                        v.x = acc2[bt][4 * rg + 0] + bias.x;
                        v.y = acc2[bt][4 * rg + 1] + bias.y;
                        v.z = acc2[bt][4 * rg + 2] + bias.z;
                        v.w = acc2[bt][4 * rg + 3] + bias.w;
                        *(float4*)(net + (gb + bt * 32 + ln) * NSTR + n0) = v;
                    }
                }
        }
    };

    auto PH3 = [&](int gb) {   // vals = ||M^T x||^2 + eps||x||^2, 8 thr/row
        const int r  = gb + (tid >> 3);
        const int jg = tid & 7;
        const float* xp = points + (row0 + r) * 16;
        float xv[16];
#pragma unroll
        for (int i = 0; i < 4; ++i) {
            float4 v = ((const float4*)xp)[i];
            xv[i * 4 + 0] = v.x; xv[i * 4 + 1] = v.y;
            xv[i * 4 + 2] = v.z; xv[i * 4 + 3] = v.w;
        }
        float sumsq = 0.f;
#pragma unroll
        for (int i = 0; i < 16; ++i) sumsq += xv[i] * xv[i];
        float p = 0.f;
#pragma unroll
        for (int jj = 0; jj < 2; ++jj) {
            const int j = jg + jj * 8;
            float y = 0.f;
#pragma unroll
            for (int i = 0; i < 16; ++i) {
                float mv = net[r * NSTR + ((i * (i + 1)) >> 1) + j];
                y += (i >= j) ? mv * xv[i] : 0.f;
            }
            p += y * y;
        }
        p += __shfl_xor(p, 1);
        p += __shfl_xor(p, 2);
        p += __shfl_xor(p, 4);
        if (jg == 0) out[row0 + r] = p + 1e-6f * sumsq;
    };

#define SEP asm volatile("" ::: "memory")

    // ---- anti-phased segment schedule (LDS rows disjoint per segment) ----
    f32x16 acc_a[2][2], acc_b[2][2], acc2_a[2], acc2_b[2];

    PH0(0);                                          // S0
    __syncthreads();
    if (w < 4) { P1M(0, acc_a); SEP; PH0(64); }      // S1: MFMA(g0) || VALU(g1)
    else       { PH0(64); SEP; P1M(0, acc_a); }
    __syncthreads();
    if (w < 4) { P1M(64, acc_b); SEP; P1E(0, acc_a); }   // S2
    else       { P1E(0, acc_a); SEP; P1M(64, acc_b); }
    __syncthreads();
    if (w < 4) { P2M(0, acc2_a); SEP; P1E(64, acc_b); }  // S3
    else       { P1E(64, acc_b); SEP; P2M(0, acc2_a); }
    __syncthreads();
    if (w < 4) { P2M(64, acc2_b); SEP; P2E(0, acc2_a); } // S4
    else       { P2E(0, acc2_a); SEP; P2M(64, acc2_b); }
    __syncthreads();
    P2E(64, acc2_b); SEP; PH3(0);                    // S5: disjoint net rows
    __syncthreads();
    PH3(64);                                         // S6
#undef SEP
}

extern "C" void kernel_launch(void* const* d_in, const int* in_sizes, int n_in,
                              void* d_out, int out_size, void* d_ws, size_t ws_size,
                              hipStream_t stream) {
    const float* points = (const float*)d_in[0];
    const float* W0 = (const float*)d_in[1];
    const float* b0 = (const float*)d_in[2];
    const float* W1 = (const float*)d_in[3];
    const float* b1 = (const float*)d_in[4];
    const float* W2 = (const float*)d_in[5];
    const float* b2 = (const float*)d_in[6];
    __bf16* ws = (__bf16*)d_ws;
    float* out = (float*)d_out;

    prep_weights<<<86, 512, 0, stream>>>(W0, W1, W2, ws);

    const int B = in_sizes[0] / 16;   // 131072
    fused_mlp_quad<<<B / 128, 512, 0, stream>>>(points, b0, b1, b2, ws, out);
}

// Round 4
// 200.339 us; speedup vs baseline: 1.0143x; 1.0143x over previous
//
#include <hip/hip_runtime.h>

typedef __bf16 bf16x4 __attribute__((ext_vector_type(4)));
typedef __bf16 bf16x8 __attribute__((ext_vector_type(8)));
typedef float f32x16 __attribute__((ext_vector_type(16)));

#define TC 2.885390081777926f   // 2/ln2, folded into W0/W1 at prep

// ---- workspace layout (bf16 element offsets), FRAGMENT-ORDERED weights ----
// 1 KB record per (nt,kk): elem (lane,j) at rec*512 + lane*8 + j
//   n = nt*32 + (lane&31), k = kk*16 + (lane>>5)*8 + j
#define W0F_OFF 0                 // 16 recs
#define W1F_OFF 8192              // 512 recs
#define W2F_OFF (8192 + 262144)   // 160 recs (n>=136 zero)

// One wave per 1KB record: coalesced row reads, coalesced dwordx4 stores.
// W0/W1 pre-scaled by TC (tanh exp2 scale) -> saves 1 VALU/tanh in the kernel.
__global__ void prep_weights(const float* __restrict__ W0,
                             const float* __restrict__ W1,
                             const float* __restrict__ W2,
                             __bf16* __restrict__ ws) {
    const int wave = blockIdx.x * 8 + (threadIdx.x >> 6);   // 0..687
    const int l   = threadIdx.x & 63;
    const int col = l & 31, kh = l >> 5;
    const float* src; int nt, kk, S, nlim; float scl;
    if (wave < 16)       { src = W0; nt = wave; kk = 0;      S = 512; nlim = 512; scl = TC; }
    else if (wave < 528) { int r = wave - 16;  src = W1; nt = r >> 5; kk = r & 31; S = 512; nlim = 512; scl = TC; }
    else                 { int r = wave - 528; src = W2; nt = r >> 5; kk = r & 31; S = 136; nlim = 136; scl = 1.0f; }
    const int n  = nt * 32 + col;
    const int k0 = kk * 16 + kh * 8;
    bf16x8 v;
#pragma unroll
    for (int j = 0; j < 8; ++j)
        v[j] = (n < nlim) ? (__bf16)(src[(k0 + j) * S + n] * scl) : (__bf16)0.0f;
    *(bf16x8*)(ws + wave * 512 + l * 8) = v;
}

// input y is pre-scaled by TC: tanh(x) = 1 - 2/(exp2(TC*x)+1)
__device__ __forceinline__ float fast_tanh_pre(float y) {
#if __has_builtin(__builtin_amdgcn_exp2f)
    float e = __builtin_amdgcn_exp2f(y);
#else
    float e = exp2f(y);
#endif
    return 1.0f - 2.0f * __builtin_amdgcn_rcpf(e + 1.0f);
}

// h LDS: [128][520] bf16 (rows 1040 B; stride 260 dw = 4 mod 32 banks, 2-way max).
// net LDS: [128][140] f32 overlay, liveness staggered per 64-row half.
#define HSTR 520
#define NSTR 140

// R21: ANTI-PHASED HALVES, SPILL-FREE. R20's anti-phase died of scratch spills
// (WRITE_SIZE 0.5->10 MB proved it): lambdas + f32x16 arrays blocked AGPR
// placement. R21 re-expresses the same m114 mechanism (each SIMD always hosts
// one MFMA-mode and one VALU-mode wave; time=max not sum) with R17's proven
// 136us per-half geometry (BM half=64, 2nt x 2bt, bt=2 -> 512 B/MFMA weight
// traffic unchanged) and straight-line macros + NAMED f32x16 accumulators
// (AGPR-eligible). Order flip (w<4 MFMA-first / w>=4 VALU-first) on the 3
// heavy segments only. Peak live regs ~190 < 256 @ 2 waves/SIMD.
// Spill tripwire: WRITE_SIZE must stay ~512 KB.
__global__ __launch_bounds__(512, 2)
void fused_mlp_quad(const float* __restrict__ points,
                    const float* __restrict__ b0,
                    const float* __restrict__ b1,
                    const float* __restrict__ b2,
                    const __bf16* __restrict__ ws,
                    float* __restrict__ out) {
    __shared__ __align__(16) unsigned char lds_raw[133120];
    __bf16* h  = (__bf16*)lds_raw;   // [128][HSTR] bf16
    float* net = (float*)lds_raw;    // [128][NSTR] f32 overlay

    const __bf16* w0f = ws + W0F_OFF;
    const __bf16* w1f = ws + W1F_OFF;
    const __bf16* w2f = ws + W2F_OFF;

    const int tid = threadIdx.x;
    const int w   = tid >> 6;
    const int l   = tid & 63;
    const int ln  = l & 31;
    const int hi  = l >> 5;
    const int row0 = blockIdx.x * 128;

    const int lofs = l * 8;
    const int ofs16 = (blockIdx.x >> 3) & 15;
    const int ofs8  = (blockIdx.x >> 3) & 7;

    const int nt2 = w >> 1;          // P2 roles (R17)
    const int bt2 = w & 1;
    const bool two = (w < 2);

    const f32x16 fzero = {};

#define MFMA32(a, b, c) __builtin_amdgcn_mfma_f32_32x32x16_bf16(a, b, c, 0, 0, 0)
#define SEP asm volatile("" ::: "memory")

// ---------- phase 0: h0 = tanh(x @ W0' + TC*b0) for 64-row half gb ----------
#define PH0(gb) do {                                                          \
    bf16x8 bx0, bx1;                                                          \
    {   const float* src = points + (row0 + (gb) + ln) * 16 + hi * 8;         \
        float4 p0 = ((const float4*)src)[0], p1 = ((const float4*)src)[1];    \
        bf16x8 v;                                                             \
        v[0]=(__bf16)p0.x; v[1]=(__bf16)p0.y; v[2]=(__bf16)p0.z; v[3]=(__bf16)p0.w; \
        v[4]=(__bf16)p1.x; v[5]=(__bf16)p1.y; v[6]=(__bf16)p1.z; v[7]=(__bf16)p1.w; \
        bx0 = v; }                                                            \
    {   const float* src = points + (row0 + (gb) + 32 + ln) * 16 + hi * 8;    \
        float4 p0 = ((const float4*)src)[0], p1 = ((const float4*)src)[1];    \
        bf16x8 v;                                                             \
        v[0]=(__bf16)p0.x; v[1]=(__bf16)p0.y; v[2]=(__bf16)p0.z; v[3]=(__bf16)p0.w; \
        v[4]=(__bf16)p1.x; v[5]=(__bf16)p1.y; v[6]=(__bf16)p1.z; v[7]=(__bf16)p1.w; \
        bx1 = v; }                                                            \
    _Pragma("unroll")                                                         \
    for (int t = 0; t < 2; ++t) {                                             \
        const int ntg = w * 2 + t;                                            \
        bf16x8 wf = *(const bf16x8*)(w0f + ntg * 512 + lofs);                 \
        f32x16 ac0 = {}, ac1 = {};                                            \
        ac0 = MFMA32(wf, bx0, ac0);                                           \
        ac1 = MFMA32(wf, bx1, ac1);                                           \
        _Pragma("unroll")                                                     \
        for (int rg = 0; rg < 4; ++rg) {                                      \
            const int n0 = ntg * 32 + 8 * rg + 4 * hi;                        \
            float4 bias = *(const float4*)(b0 + n0);                          \
            bf16x4 v;                                                         \
            v[0]=(__bf16)fast_tanh_pre(fmaf(TC,bias.x,ac0[4*rg+0]));          \
            v[1]=(__bf16)fast_tanh_pre(fmaf(TC,bias.y,ac0[4*rg+1]));          \
            v[2]=(__bf16)fast_tanh_pre(fmaf(TC,bias.z,ac0[4*rg+2]));          \
            v[3]=(__bf16)fast_tanh_pre(fmaf(TC,bias.w,ac0[4*rg+3]));          \
            *(bf16x4*)(h + ((gb) + ln) * HSTR + n0) = v;                      \
            v[0]=(__bf16)fast_tanh_pre(fmaf(TC,bias.x,ac1[4*rg+0]));          \
            v[1]=(__bf16)fast_tanh_pre(fmaf(TC,bias.y,ac1[4*rg+1]));          \
            v[2]=(__bf16)fast_tanh_pre(fmaf(TC,bias.z,ac1[4*rg+2]));          \
            v[3]=(__bf16)fast_tanh_pre(fmaf(TC,bias.w,ac1[4*rg+3]));          \
            *(bf16x4*)(h + ((gb) + 32 + ln) * HSTR + n0) = v;                 \
        }                                                                     \
    }                                                                         \
} while (0)

// ---------- P1 MFMA: A_bt_t = h0 @ W1' (half gb), 512 B/MFMA, rotated ----------
#define P1M(gb, A00, A01, A10, A11) do {                                      \
    A00 = fzero; A01 = fzero; A10 = fzero; A11 = fzero;                       \
    const __bf16* arow0 = h + ((gb) + ln) * HSTR + hi * 8;                    \
    const __bf16* arow1 = h + ((gb) + 32 + ln) * HSTR + hi * 8;               \
    const __bf16* wb0 = w1f + (w * 2 + 0) * 16384 + lofs;                     \
    const __bf16* wb1 = w1f + (w * 2 + 1) * 16384 + lofs;                     \
    for (int ks2 = 0; ks2 < 16; ++ks2) {                                      \
        const int ks = (ks2 + ofs16) & 15;                                    \
        bf16x8 aa00, aa01, aa10, aa11, bb00, bb01, bb10, bb11;                \
        {   const int kk = ks * 2;                                            \
            aa00 = *(const bf16x8*)(arow0 + kk * 16);                         \
            aa01 = *(const bf16x8*)(arow1 + kk * 16);                         \
            bb00 = *(const bf16x8*)(wb0 + kk * 512);                          \
            bb01 = *(const bf16x8*)(wb1 + kk * 512); }                        \
        {   const int kk = ks * 2 + 1;                                        \
            aa10 = *(const bf16x8*)(arow0 + kk * 16);                         \
            aa11 = *(const bf16x8*)(arow1 + kk * 16);                         \
            bb10 = *(const bf16x8*)(wb0 + kk * 512);                          \
            bb11 = *(const bf16x8*)(wb1 + kk * 512); }                        \
        A00 = MFMA32(bb00, aa00, A00);  A01 = MFMA32(bb01, aa00, A01);        \
        A10 = MFMA32(bb00, aa01, A10);  A11 = MFMA32(bb01, aa01, A11);        \
        A00 = MFMA32(bb10, aa10, A00);  A01 = MFMA32(bb11, aa10, A01);        \
        A10 = MFMA32(bb10, aa11, A10);  A11 = MFMA32(bb11, aa11, A11);        \
    }                                                                         \
} while (0)

// ---------- P1 epilogue: h1 = tanh(A + TC*b1) into half gb ----------
#define P1E(gb, A00, A01, A10, A11) do {                                      \
    _Pragma("unroll")                                                         \
    for (int rg = 0; rg < 4; ++rg) {                                          \
        const int n0a = (w * 2 + 0) * 32 + 8 * rg + 4 * hi;                   \
        const int n0b = (w * 2 + 1) * 32 + 8 * rg + 4 * hi;                   \
        float4 ba = *(const float4*)(b1 + n0a);                               \
        float4 bb = *(const float4*)(b1 + n0b);                               \
        bf16x4 v;                                                             \
        v[0]=(__bf16)fast_tanh_pre(fmaf(TC,ba.x,A00[4*rg+0]));                \
        v[1]=(__bf16)fast_tanh_pre(fmaf(TC,ba.y,A00[4*rg+1]));                \
        v[2]=(__bf16)fast_tanh_pre(fmaf(TC,ba.z,A00[4*rg+2]));                \
        v[3]=(__bf16)fast_tanh_pre(fmaf(TC,ba.w,A00[4*rg+3]));                \
        *(bf16x4*)(h + ((gb) + ln) * HSTR + n0a) = v;                         \
        v[0]=(__bf16)fast_tanh_pre(fmaf(TC,bb.x,A01[4*rg+0]));                \
        v[1]=(__bf16)fast_tanh_pre(fmaf(TC,bb.y,A01[4*rg+1]));                \
        v[2]=(__bf16)fast_tanh_pre(fmaf(TC,bb.z,A01[4*rg+2]));                \
        v[3]=(__bf16)fast_tanh_pre(fmaf(TC,bb.w,A01[4*rg+3]));                \
        *(bf16x4*)(h + ((gb) + ln) * HSTR + n0b) = v;                         \
        v[0]=(__bf16)fast_tanh_pre(fmaf(TC,ba.x,A10[4*rg+0]));                \
        v[1]=(__bf16)fast_tanh_pre(fmaf(TC,ba.y,A10[4*rg+1]));                \
        v[2]=(__bf16)fast_tanh_pre(fmaf(TC,ba.z,A10[4*rg+2]));                \
        v[3]=(__bf16)fast_tanh_pre(fmaf(TC,ba.w,A10[4*rg+3]));                \
        *(bf16x4*)(h + ((gb) + 32 + ln) * HSTR + n0a) = v;                    \
        v[0]=(__bf16)fast_tanh_pre(fmaf(TC,bb.x,A11[4*rg+0]));                \
        v[1]=(__bf16)fast_tanh_pre(fmaf(TC,bb.y,A11[4*rg+1]));                \
        v[2]=(__bf16)fast_tanh_pre(fmaf(TC,bb.z,A11[4*rg+2]));                \
        v[3]=(__bf16)fast_tanh_pre(fmaf(TC,bb.w,A11[4*rg+3]));                \
        *(bf16x4*)(h + ((gb) + 32 + ln) * HSTR + n0b) = v;                    \
    }                                                                         \
} while (0)

// ---------- P2 MFMA: net-acc for half gb (R17 10-tile layout) ----------
#define P2M(gb, CA, CE) do {                                                  \
    CA = fzero; CE = fzero;                                                   \
    const __bf16* arowA = h + ((gb) + bt2 * 32 + ln) * HSTR + hi * 8;         \
    const __bf16* arowE = h + ((gb) + (w & 1) * 32 + ln) * HSTR + hi * 8;     \
    const __bf16* wbA = w2f + nt2 * 16384 + lofs;                             \
    const __bf16* wbE = w2f + 4 * 16384 + lofs;                               \
    for (int ks2 = 0; ks2 < 8; ++ks2) {                                       \
        const int ks = (ks2 + ofs8) & 7;                                      \
        bf16x8 aA0, wA0, aA1, wA1, aA2, wA2, aA3, wA3;                        \
        bf16x8 aE0 = {}, wE0 = {}, aE1 = {}, wE1 = {}, aE2 = {}, wE2 = {}, aE3 = {}, wE3 = {}; \
        {   const int kk = ks * 4;                                            \
            aA0 = *(const bf16x8*)(arowA + kk * 16); wA0 = *(const bf16x8*)(wbA + kk * 512);       \
            aA1 = *(const bf16x8*)(arowA + (kk+1)*16); wA1 = *(const bf16x8*)(wbA + (kk+1)*512);   \
            aA2 = *(const bf16x8*)(arowA + (kk+2)*16); wA2 = *(const bf16x8*)(wbA + (kk+2)*512);   \
            aA3 = *(const bf16x8*)(arowA + (kk+3)*16); wA3 = *(const bf16x8*)(wbA + (kk+3)*512);   \
            if (two) {                                                        \
                aE0 = *(const bf16x8*)(arowE + kk * 16); wE0 = *(const bf16x8*)(wbE + kk * 512);   \
                aE1 = *(const bf16x8*)(arowE + (kk+1)*16); wE1 = *(const bf16x8*)(wbE + (kk+1)*512); \
                aE2 = *(const bf16x8*)(arowE + (kk+2)*16); wE2 = *(const bf16x8*)(wbE + (kk+2)*512); \
                aE3 = *(const bf16x8*)(arowE + (kk+3)*16); wE3 = *(const bf16x8*)(wbE + (kk+3)*512); \
            } }                                                               \
        CA = MFMA32(wA0, aA0, CA); CA = MFMA32(wA1, aA1, CA);                 \
        CA = MFMA32(wA2, aA2, CA); CA = MFMA32(wA3, aA3, CA);                 \
        if (two) {                                                            \
            CE = MFMA32(wE0, aE0, CE); CE = MFMA32(wE1, aE1, CE);             \
            CE = MFMA32(wE2, aE2, CE); CE = MFMA32(wE3, aE3, CE);             \
        }                                                                     \
    }                                                                         \
} while (0)

// ---------- P2 epilogue: net = C + b2 (f32) for half gb ----------
#define P2E(gb, CA, CE) do {                                                  \
    _Pragma("unroll")                                                         \
    for (int rg = 0; rg < 4; ++rg) {                                          \
        const int n0 = nt2 * 32 + 8 * rg + 4 * hi;                            \
        float4 bias = *(const float4*)(b2 + n0);                              \
        float4 v;                                                             \
        v.x = CA[4*rg+0] + bias.x; v.y = CA[4*rg+1] + bias.y;                 \
        v.z = CA[4*rg+2] + bias.z; v.w = CA[4*rg+3] + bias.w;                 \
        *(float4*)(net + ((gb) + bt2 * 32 + ln) * NSTR + n0) = v;             \
    }                                                                         \
    if (two) {                                                                \
        const int n0 = 128 + 4 * hi;                                          \
        float4 bias = *(const float4*)(b2 + n0);                              \
        float4 v;                                                             \
        v.x = CE[0] + bias.x; v.y = CE[1] + bias.y;                           \
        v.z = CE[2] + bias.z; v.w = CE[3] + bias.w;                           \
        *(float4*)(net + ((gb) + (w & 1) * 32 + ln) * NSTR + n0) = v;         \
    }                                                                         \
} while (0)

// ---------- P3: vals for half gb (8 thr/row x 64 rows) ----------
#define PH3(gb) do {                                                          \
    const int rl = tid >> 3;                                                  \
    const int jg = tid & 7;                                                   \
    const float* xp = points + (row0 + (gb) + rl) * 16;                       \
    float xv[16];                                                             \
    _Pragma("unroll")                                                         \
    for (int i = 0; i < 4; ++i) {                                             \
        float4 v = ((const float4*)xp)[i];                                    \
        xv[i*4+0] = v.x; xv[i*4+1] = v.y; xv[i*4+2] = v.z; xv[i*4+3] = v.w;   \
    }                                                                         \
    float sumsq = 0.f;                                                        \
    _Pragma("unroll")                                                         \
    for (int i = 0; i < 16; ++i) sumsq += xv[i] * xv[i];                      \
    float p = 0.f;                                                            \
    _Pragma("unroll")                                                         \
    for (int jj = 0; jj < 2; ++jj) {                                          \
        const int j = jg + jj * 8;                                            \
        float y = 0.f;                                                        \
        _Pragma("unroll")                                                     \
        for (int i = 0; i < 16; ++i) {                                        \
            float mv = net[((gb) + rl) * NSTR + ((i * (i + 1)) >> 1) + j];    \
            y += (i >= j) ? mv * xv[i] : 0.f;                                 \
        }                                                                     \
        p += y * y;                                                           \
    }                                                                         \
    p += __shfl_xor(p, 1);                                                    \
    p += __shfl_xor(p, 2);                                                    \
    p += __shfl_xor(p, 4);                                                    \
    if (jg == 0) out[row0 + (gb) + rl] = p + 1e-6f * sumsq;                   \
} while (0)

    // ---------- anti-phased schedule over halves A(gb=0), B(gb=64) ----------
    f32x16 a1A00, a1A01, a1A10, a1A11;
    f32x16 a1B00, a1B01, a1B10, a1B11;
    f32x16 c2aA, c2eA, c2aB, c2eB;

    PH0(0);                                              // S0
    __syncthreads();
    if (w < 4) { P1M(0, a1A00, a1A01, a1A10, a1A11); SEP; PH0(64); }
    else       { PH0(64); SEP; P1M(0, a1A00, a1A01, a1A10, a1A11); }
    __syncthreads();                                     // S1
    if (w < 4) { P1M(64, a1B00, a1B01, a1B10, a1B11); SEP; P1E(0, a1A00, a1A01, a1A10, a1A11); }
    else       { P1E(0, a1A00, a1A01, a1A10, a1A11); SEP; P1M(64, a1B00, a1B01, a1B10, a1B11); }
    __syncthreads();                                     // S2
    if (w < 4) { P2M(0, c2aA, c2eA); SEP; P1E(64, a1B00, a1B01, a1B10, a1B11); }
    else       { P1E(64, a1B00, a1B01, a1B10, a1B11); SEP; P2M(0, c2aA, c2eA); }
    __syncthreads();                                     // S3
    P2M(64, c2aB, c2eB); SEP; P2E(0, c2aA, c2eA);        // S4 (P2E tiny)
    __syncthreads();
    PH3(0); SEP; P2E(64, c2aB, c2eB);                    // S5 (disjoint net rows)
    __syncthreads();
    PH3(64);                                             // S6
}

extern "C" void kernel_launch(void* const* d_in, const int* in_sizes, int n_in,
                              void* d_out, int out_size, void* d_ws, size_t ws_size,
                              hipStream_t stream) {
    const float* points = (const float*)d_in[0];
    const float* W0 = (const float*)d_in[1];
    const float* b0 = (const float*)d_in[2];
    const float* W1 = (const float*)d_in[3];
    const float* b1 = (const float*)d_in[4];
    const float* W2 = (const float*)d_in[5];
    const float* b2 = (const float*)d_in[6];
    __bf16* ws = (__bf16*)d_ws;
    float* out = (float*)d_out;

    prep_weights<<<86, 512, 0, stream>>>(W0, W1, W2, ws);

    const int B = in_sizes[0] / 16;   // 131072
    fused_mlp_quad<<<B / 128, 512, 0, stream>>>(points, b0, b1, b2, ws, out);
}